// Round 4
// baseline (233.615 us; speedup 1.0000x reference)
//
#include <hip/hip_runtime.h>
#include <hip/hip_cooperative_groups.h>
namespace cg = cooperative_groups;

#define HIDDEN 64
#define NB 4            // destination buckets
#define BS 25000        // nodes per bucket (NB*BS == N exactly) -> 100 KB LDS
#define NT 1024         // threads per block
#define NS 64           // edge slices per bucket
#define NBLK (NB * NS)  // 256 blocks == 256 CUs, 1 block/CU (coop-resident)
#define RSTRIDE (NB * BS)  // float stride between replicas of same node

// replica layout: racc[(b*NB + g)*BS + li]  == racc[g*BS + li + b*RSTRIDE]

__global__ __launch_bounds__(NT, 1) void gcn_fused(
    const float* __restrict__ x, const int* __restrict__ src,
    const int* __restrict__ dst, const float* __restrict__ W1,
    const float* __restrict__ b1, const float* __restrict__ W2,
    const float* __restrict__ b2, float* __restrict__ out,
    float* __restrict__ dinv, float* __restrict__ xs, float* __restrict__ h2s,
    float* __restrict__ racc, int n, int e)
{
    __shared__ alignas(16) float lacc[BS];
    __shared__ float swt[3 * HIDDEN];
    cg::grid_group grid = cg::this_grid();

    const int bid = blockIdx.x;
    const int g = bid & (NB - 1);   // bucket
    const int b = bid >> 2;         // slice
    const int base = g * BS;
    const int tid = threadIdx.x;

    const int E4 = e >> 2;  // e % 4 == 0 for this problem; tail handled below
    const int q_lo = (int)((long long)E4 * b / NS);
    const int q_hi = (int)((long long)E4 * (b + 1) / NS);
    float* rep = racc + (size_t)bid * BS;
    const int node = bid * NT + tid;   // one node per thread for node phases

    // ---- phase 1: degree counting -------------------------------------
    for (int i = tid; i < BS / 4; i += NT) ((float4*)lacc)[i] = make_float4(0, 0, 0, 0);
    __syncthreads();
    for (int q = q_lo + tid; q < q_hi; q += NT) {
        int4 d4 = ((const int4*)dst)[q];
        int a0 = d4.x - base, a1 = d4.y - base, a2 = d4.z - base, a3 = d4.w - base;
        if ((unsigned)a0 < (unsigned)BS) atomicAdd(&lacc[a0], 1.0f);
        if ((unsigned)a1 < (unsigned)BS) atomicAdd(&lacc[a1], 1.0f);
        if ((unsigned)a2 < (unsigned)BS) atomicAdd(&lacc[a2], 1.0f);
        if ((unsigned)a3 < (unsigned)BS) atomicAdd(&lacc[a3], 1.0f);
    }
    if (bid == 0) {  // tail edges (e % 4), counted once by block 0
        for (int i = (E4 << 2) + tid; i < e; i += NT) {
            int d = dst[i] - base;
            if ((unsigned)d < (unsigned)BS) atomicAdd(&lacc[d], 1.0f);
        }
    }
    __syncthreads();
    for (int i = tid; i < BS / 4; i += NT) ((float4*)rep)[i] = ((float4*)lacc)[i];
    grid.sync();

    // ---- phase 2: dinv = rsqrt(1 + deg), xs = x*dinv ------------------
    if (node < n) {
        int gg = node / BS, li = node - gg * BS;
        const float* r = racc + gg * BS + li;
        float s = 1.0f;
#pragma unroll 8
        for (int k = 0; k < NS; ++k) s += r[(size_t)k * RSTRIDE];
        float d = rsqrtf(s);
        dinv[node] = d;
        xs[node] = x[node] * d;
    }
    grid.sync();

    // ---- phase 3: scatter xs ------------------------------------------
    for (int i = tid; i < BS / 4; i += NT) ((float4*)lacc)[i] = make_float4(0, 0, 0, 0);
    __syncthreads();
    for (int q = q_lo + tid; q < q_hi; q += NT) {
        int4 s4 = ((const int4*)src)[q];
        int4 d4 = ((const int4*)dst)[q];
        int a0 = d4.x - base, a1 = d4.y - base, a2 = d4.z - base, a3 = d4.w - base;
        if ((unsigned)a0 < (unsigned)BS) atomicAdd(&lacc[a0], xs[s4.x]);
        if ((unsigned)a1 < (unsigned)BS) atomicAdd(&lacc[a1], xs[s4.y]);
        if ((unsigned)a2 < (unsigned)BS) atomicAdd(&lacc[a2], xs[s4.z]);
        if ((unsigned)a3 < (unsigned)BS) atomicAdd(&lacc[a3], xs[s4.w]);
    }
    if (bid == 0) {
        for (int i = (E4 << 2) + tid; i < e; i += NT) {
            int d = dst[i] - base;
            if ((unsigned)d < (unsigned)BS) atomicAdd(&lacc[d], xs[src[i]]);
        }
    }
    __syncthreads();
    for (int i = tid; i < BS / 4; i += NT) ((float4*)rep)[i] = ((float4*)lacc)[i];
    grid.sync();

    // ---- phase 4: per-node MLP, h2s = dinv * MLP(s1) ------------------
    if (tid < HIDDEN) {
        swt[tid] = W1[tid];
        swt[HIDDEN + tid] = b1[tid];
        swt[2 * HIDDEN + tid] = W2[tid];
    }
    __syncthreads();
    if (node < n) {
        int gg = node / BS, li = node - gg * BS;
        const float* r = racc + gg * BS + li;
        float s = xs[node];  // self-loop term (already x*dinv)
#pragma unroll 8
        for (int k = 0; k < NS; ++k) s += r[(size_t)k * RSTRIDE];
        float di = dinv[node];
        float s1 = di * s;
        float h = 0.0f;
#pragma unroll
        for (int j = 0; j < HIDDEN; ++j)
            h += fmaxf(fmaf(s1, swt[j], swt[HIDDEN + j]), 0.0f) * swt[2 * HIDDEN + j];
        h2s[node] = h * di;
    }
    grid.sync();

    // ---- phase 5: scatter h2s -----------------------------------------
    for (int i = tid; i < BS / 4; i += NT) ((float4*)lacc)[i] = make_float4(0, 0, 0, 0);
    __syncthreads();
    for (int q = q_lo + tid; q < q_hi; q += NT) {
        int4 s4 = ((const int4*)src)[q];
        int4 d4 = ((const int4*)dst)[q];
        int a0 = d4.x - base, a1 = d4.y - base, a2 = d4.z - base, a3 = d4.w - base;
        if ((unsigned)a0 < (unsigned)BS) atomicAdd(&lacc[a0], h2s[s4.x]);
        if ((unsigned)a1 < (unsigned)BS) atomicAdd(&lacc[a1], h2s[s4.y]);
        if ((unsigned)a2 < (unsigned)BS) atomicAdd(&lacc[a2], h2s[s4.z]);
        if ((unsigned)a3 < (unsigned)BS) atomicAdd(&lacc[a3], h2s[s4.w]);
    }
    if (bid == 0) {
        for (int i = (E4 << 2) + tid; i < e; i += NT) {
            int d = dst[i] - base;
            if ((unsigned)d < (unsigned)BS) atomicAdd(&lacc[d], h2s[src[i]]);
        }
    }
    __syncthreads();
    for (int i = tid; i < BS / 4; i += NT) ((float4*)rep)[i] = ((float4*)lacc)[i];
    grid.sync();

    // ---- phase 6: output ----------------------------------------------
    if (node < n) {
        int gg = node / BS, li = node - gg * BS;
        const float* r = racc + gg * BS + li;
        float s = h2s[node];  // self-loop term
#pragma unroll 8
        for (int k = 0; k < NS; ++k) s += r[(size_t)k * RSTRIDE];
        out[node] = dinv[node] * s + b2[0];
    }
}

// ---------------- fallback: single-copy global-atomic path ----------------

__global__ void f_init(float* deg, float* agg, int n) {
    int i = blockIdx.x * blockDim.x + threadIdx.x;
    if (i < n) { deg[i] = 1.0f; agg[i] = 0.0f; }
}
__global__ void f_deg(const int* __restrict__ dst, float* deg, int e) {
    int i = blockIdx.x * blockDim.x + threadIdx.x;
    if (i < e) atomicAdd(&deg[dst[i]], 1.0f);
}
__global__ void f_prep(const float* __restrict__ x, float* deg,
                       float* __restrict__ xs, int n) {
    int i = blockIdx.x * blockDim.x + threadIdx.x;
    if (i < n) { float d = rsqrtf(deg[i]); deg[i] = d; xs[i] = x[i] * d; }
}
__global__ void f_scat(const int* __restrict__ src, const int* __restrict__ dst,
                       const float* __restrict__ vals, float* agg, int e) {
    int i = blockIdx.x * blockDim.x + threadIdx.x;
    if (i < e) atomicAdd(&agg[dst[i]], vals[src[i]]);
}
__global__ void f_mlp(const float* __restrict__ dinv, const float* __restrict__ xs,
                      float* agg, const float* __restrict__ W1,
                      const float* __restrict__ b1, const float* __restrict__ W2,
                      float* __restrict__ h2s, int n) {
    __shared__ float sW1[HIDDEN], sb1[HIDDEN], sW2[HIDDEN];
    if (threadIdx.x < HIDDEN) {
        sW1[threadIdx.x] = W1[threadIdx.x];
        sb1[threadIdx.x] = b1[threadIdx.x];
        sW2[threadIdx.x] = W2[threadIdx.x];
    }
    __syncthreads();
    int i = blockIdx.x * blockDim.x + threadIdx.x;
    if (i >= n) return;
    float di = dinv[i];
    float s1 = di * (agg[i] + xs[i]);
    agg[i] = 0.0f;
    float h = 0.0f;
#pragma unroll
    for (int j = 0; j < HIDDEN; ++j)
        h += fmaxf(fmaf(s1, sW1[j], sb1[j]), 0.0f) * sW2[j];
    h2s[i] = h * di;
}
__global__ void f_out(const float* __restrict__ dinv, const float* __restrict__ h2s,
                      const float* __restrict__ agg, const float* __restrict__ b2,
                      float* __restrict__ out, int n) {
    int i = blockIdx.x * blockDim.x + threadIdx.x;
    if (i < n) out[i] = dinv[i] * (agg[i] + h2s[i]) + b2[0];
}

// ---------------------------------------------------------------------------

extern "C" void kernel_launch(void* const* d_in, const int* in_sizes, int n_in,
                              void* d_out, int out_size, void* d_ws, size_t ws_size,
                              hipStream_t stream) {
    const float* x  = (const float*)d_in[0];
    const int*   ei = (const int*)d_in[1];   // [2, E] int32
    const float* W1 = (const float*)d_in[2];
    const float* b1 = (const float*)d_in[3];
    const float* W2 = (const float*)d_in[4];
    const float* b2 = (const float*)d_in[5];
    float* out = (float*)d_out;

    const int n = in_sizes[0];
    const int e = in_sizes[1] / 2;
    const int* src = ei;
    const int* dst = ei + e;

    // ws: dinv[n], xs[n], h2s[n], racc[NBLK*BS]
    const size_t need = ((size_t)3 * n + (size_t)NBLK * BS) * sizeof(float);

    if (n == NB * BS && ws_size >= need) {
        float* dinv = (float*)d_ws;
        float* xs   = dinv + n;
        float* h2s  = xs + n;
        float* racc = h2s + n;
        int n_ = n, e_ = e;
        void* args[] = {(void*)&x,  (void*)&src, (void*)&dst, (void*)&W1,
                        (void*)&b1, (void*)&W2,  (void*)&b2,  (void*)&out,
                        (void*)&dinv, (void*)&xs, (void*)&h2s, (void*)&racc,
                        (void*)&n_, (void*)&e_};
        hipLaunchCooperativeKernel((void*)gcn_fused, dim3(NBLK), dim3(NT),
                                   args, 0, stream);
    } else {
        const int BT = 256;
        const int gn = (n + BT - 1) / BT;
        const int ge = (e + BT - 1) / BT;
        float* dinv = (float*)d_ws;   // holds deg then dinv
        float* xs   = dinv + n;
        float* h2s  = xs + n;
        float* agg  = h2s + n;
        f_init<<<gn, BT, 0, stream>>>(dinv, agg, n);
        f_deg <<<ge, BT, 0, stream>>>(dst, dinv, e);
        f_prep<<<gn, BT, 0, stream>>>(x, dinv, xs, n);
        f_scat<<<ge, BT, 0, stream>>>(src, dst, xs, agg, e);
        f_mlp <<<gn, BT, 0, stream>>>(dinv, xs, agg, W1, b1, W2, h2s, n);
        f_scat<<<ge, BT, 0, stream>>>(src, dst, h2s, agg, e);
        f_out <<<gn, BT, 0, stream>>>(dinv, h2s, agg, b2, out, n);
    }
}

// Round 5
// 100.153 us; speedup vs baseline: 2.3326x; 2.3326x over previous
//
#include <hip/hip_runtime.h>

#define HIDDEN 64
#define BSN 512          // nodes per bucket (power of 2)
#define LOGB 9
#define NTILES 128       // sort tiles
#define NTS 1024         // threads for hist/scan/sort kernels
#define NTE 1024         // threads for bucket (edge) kernels
#define MAXB 4096        // max buckets supported by LDS counters (16 KB)

// ---------- pass 1: per-tile per-bucket histogram --------------------------
__global__ __launch_bounds__(NTS) void k_hist(const int* __restrict__ dst, int e,
                                              int nbuck, int* __restrict__ counts) {
    __shared__ int lcnt[MAXB];
    const int t = blockIdx.x;
    for (int i = threadIdx.x; i < nbuck; i += NTS) lcnt[i] = 0;
    __syncthreads();
    const int lo = (int)((long long)e * t / NTILES);
    const int hi = (int)((long long)e * (t + 1) / NTILES);
    for (int i = lo + threadIdx.x; i < hi; i += NTS)
        atomicAdd(&lcnt[dst[i] >> LOGB], 1);
    __syncthreads();
    for (int g = threadIdx.x; g < nbuck; g += NTS)
        counts[g * NTILES + t] = lcnt[g];
}

// ---------- pass 2: exclusive scan (bucket-major) + bucket starts ----------
__global__ __launch_bounds__(NTS) void k_scan(const int* __restrict__ counts,
                                              int* __restrict__ offs,
                                              int* __restrict__ bstart,
                                              int nbuck, int e) {
    __shared__ int ssum[NTS];
    __shared__ int sexc[NTS];
    const int M = nbuck * NTILES;
    const int chunk = (M + NTS - 1) / NTS;
    const int t = threadIdx.x;
    const int lo = t * chunk;
    const int hi = lo + chunk < M ? lo + chunk : M;
    int s = 0;
    for (int i = lo; i < hi; ++i) s += counts[i];
    ssum[t] = s;
    __syncthreads();
    if (t == 0) {
        int run = 0;
        for (int i = 0; i < NTS; ++i) { sexc[i] = run; run += ssum[i]; }
    }
    __syncthreads();
    int running = sexc[t];
    for (int i = lo; i < hi; ++i) { offs[i] = running; running += counts[i]; }
    __threadfence_block();
    __syncthreads();
    for (int g = t; g < nbuck; g += NTS) bstart[g] = offs[g * NTILES];
    if (t == 0) bstart[nbuck] = e;
}

// ---------- pass 3: scatter edges into bucket-sorted order -----------------
__global__ __launch_bounds__(NTS) void k_sortB(const int* __restrict__ src,
                                               const int* __restrict__ dst, int e,
                                               int nbuck, const int* __restrict__ offs,
                                               int* __restrict__ ssrc,
                                               int* __restrict__ sdst) {
    __shared__ int loffs[MAXB];
    const int t = blockIdx.x;
    for (int g = threadIdx.x; g < nbuck; g += NTS) loffs[g] = offs[g * NTILES + t];
    __syncthreads();
    const int lo = (int)((long long)e * t / NTILES);
    const int hi = (int)((long long)e * (t + 1) / NTILES);
    for (int i = lo + threadIdx.x; i < hi; i += NTS) {
        int d = dst[i];
        int g = d >> LOGB;
        int pos = atomicAdd(&loffs[g], 1);
        ssrc[pos] = src[i];
        sdst[pos] = d;
    }
}

// ---------- pass 4: degree -> dinv, xs  (one block per bucket) -------------
__global__ __launch_bounds__(NTE) void k_deg_prep(const int* __restrict__ sdst,
                                                  const int* __restrict__ bstart,
                                                  const float* __restrict__ x,
                                                  float* __restrict__ dinv,
                                                  float* __restrict__ xs, int n) {
    __shared__ float lacc[BSN];
    const int g = blockIdx.x;
    if (threadIdx.x < BSN) lacc[threadIdx.x] = 0.0f;
    __syncthreads();
    const int lo = bstart[g], hi = bstart[g + 1];
    const int base = g << LOGB;
    for (int i = lo + threadIdx.x; i < hi; i += NTE)
        atomicAdd(&lacc[sdst[i] - base], 1.0f);
    __syncthreads();
    const int node = base + threadIdx.x;
    if (threadIdx.x < BSN && node < n) {
        float d = rsqrtf(1.0f + lacc[threadIdx.x]);   // +1 = self-loop
        dinv[node] = d;
        xs[node] = x[node] * d;
    }
}

// ---------- pass 5: scatter xs -> agg -> MLP -> h2s ------------------------
__global__ __launch_bounds__(NTE) void k_scat_mlp(const int* __restrict__ ssrc,
    const int* __restrict__ sdst, const int* __restrict__ bstart,
    const float* __restrict__ dinv, const float* __restrict__ xs,
    const float* __restrict__ W1, const float* __restrict__ b1,
    const float* __restrict__ W2, float* __restrict__ h2s, int n) {
    __shared__ float lacc[BSN];
    __shared__ float swt[3 * HIDDEN];
    const int g = blockIdx.x;
    if (threadIdx.x < BSN) lacc[threadIdx.x] = 0.0f;
    if (threadIdx.x >= BSN && threadIdx.x < BSN + 3 * HIDDEN) {
        int j = threadIdx.x - BSN;
        swt[j] = (j < HIDDEN) ? W1[j]
               : (j < 2 * HIDDEN) ? b1[j - HIDDEN] : W2[j - 2 * HIDDEN];
    }
    __syncthreads();
    const int lo = bstart[g], hi = bstart[g + 1];
    const int base = g << LOGB;
    for (int i = lo + threadIdx.x; i < hi; i += NTE)
        atomicAdd(&lacc[sdst[i] - base], xs[ssrc[i]]);
    __syncthreads();
    const int node = base + threadIdx.x;
    if (threadIdx.x < BSN && node < n) {
        float di = dinv[node];
        float s1 = di * (lacc[threadIdx.x] + xs[node]);  // xs = self-loop term
        float h = 0.0f;
#pragma unroll
        for (int j = 0; j < HIDDEN; ++j)
            h += fmaxf(fmaf(s1, swt[j], swt[HIDDEN + j]), 0.0f) * swt[2 * HIDDEN + j];
        h2s[node] = h * di;
    }
}

// ---------- pass 6: scatter h2s -> agg -> out ------------------------------
__global__ __launch_bounds__(NTE) void k_scat_out(const int* __restrict__ ssrc,
    const int* __restrict__ sdst, const int* __restrict__ bstart,
    const float* __restrict__ dinv, const float* __restrict__ h2s,
    const float* __restrict__ b2, float* __restrict__ out, int n) {
    __shared__ float lacc[BSN];
    const int g = blockIdx.x;
    if (threadIdx.x < BSN) lacc[threadIdx.x] = 0.0f;
    __syncthreads();
    const int lo = bstart[g], hi = bstart[g + 1];
    const int base = g << LOGB;
    for (int i = lo + threadIdx.x; i < hi; i += NTE)
        atomicAdd(&lacc[sdst[i] - base], h2s[ssrc[i]]);
    __syncthreads();
    const int node = base + threadIdx.x;
    if (threadIdx.x < BSN && node < n)
        out[node] = dinv[node] * (lacc[threadIdx.x] + h2s[node]) + b2[0];
}

// ---------------- fallback: single-copy global-atomic path ----------------
__global__ void f_init(float* deg, float* agg, int n) {
    int i = blockIdx.x * blockDim.x + threadIdx.x;
    if (i < n) { deg[i] = 1.0f; agg[i] = 0.0f; }
}
__global__ void f_deg(const int* __restrict__ dst, float* deg, int e) {
    int i = blockIdx.x * blockDim.x + threadIdx.x;
    if (i < e) atomicAdd(&deg[dst[i]], 1.0f);
}
__global__ void f_prep(const float* __restrict__ x, float* deg,
                       float* __restrict__ xs, int n) {
    int i = blockIdx.x * blockDim.x + threadIdx.x;
    if (i < n) { float d = rsqrtf(deg[i]); deg[i] = d; xs[i] = x[i] * d; }
}
__global__ void f_scat(const int* __restrict__ src, const int* __restrict__ dst,
                       const float* __restrict__ vals, float* agg, int e) {
    int i = blockIdx.x * blockDim.x + threadIdx.x;
    if (i < e) atomicAdd(&agg[dst[i]], vals[src[i]]);
}
__global__ void f_mlp(const float* __restrict__ dinv, const float* __restrict__ xs,
                      float* agg, const float* __restrict__ W1,
                      const float* __restrict__ b1, const float* __restrict__ W2,
                      float* __restrict__ h2s, int n) {
    __shared__ float sW1[HIDDEN], sb1[HIDDEN], sW2[HIDDEN];
    if (threadIdx.x < HIDDEN) {
        sW1[threadIdx.x] = W1[threadIdx.x];
        sb1[threadIdx.x] = b1[threadIdx.x];
        sW2[threadIdx.x] = W2[threadIdx.x];
    }
    __syncthreads();
    int i = blockIdx.x * blockDim.x + threadIdx.x;
    if (i >= n) return;
    float di = dinv[i];
    float s1 = di * (agg[i] + xs[i]);
    agg[i] = 0.0f;
    float h = 0.0f;
#pragma unroll
    for (int j = 0; j < HIDDEN; ++j)
        h += fmaxf(fmaf(s1, sW1[j], sb1[j]), 0.0f) * sW2[j];
    h2s[i] = h * di;
}
__global__ void f_out(const float* __restrict__ dinv, const float* __restrict__ h2s,
                      const float* __restrict__ agg, const float* __restrict__ b2,
                      float* __restrict__ out, int n) {
    int i = blockIdx.x * blockDim.x + threadIdx.x;
    if (i < n) out[i] = dinv[i] * (agg[i] + h2s[i]) + b2[0];
}

// ---------------------------------------------------------------------------
extern "C" void kernel_launch(void* const* d_in, const int* in_sizes, int n_in,
                              void* d_out, int out_size, void* d_ws, size_t ws_size,
                              hipStream_t stream) {
    const float* x  = (const float*)d_in[0];
    const int*   ei = (const int*)d_in[1];   // [2, E] int32
    const float* W1 = (const float*)d_in[2];
    const float* b1 = (const float*)d_in[3];
    const float* W2 = (const float*)d_in[4];
    const float* b2 = (const float*)d_in[5];
    float* out = (float*)d_out;

    const int n = in_sizes[0];
    const int e = in_sizes[1] / 2;
    const int* src = ei;
    const int* dst = ei + e;

    const int nbuck = (n + BSN - 1) >> LOGB;
    const int M = nbuck * NTILES;
    // ws: dinv[n], xs[n], h2s[n] | ssrc[e], sdst[e], counts[M], offs[M], bstart[nbuck+1]
    const size_t need = ((size_t)3 * n + 2 * (size_t)e + 2 * (size_t)M + nbuck + 1)
                        * sizeof(int);

    if (nbuck >= 1 && nbuck <= MAXB && ws_size >= need) {
        float* dinv = (float*)d_ws;
        float* xs   = dinv + n;
        float* h2s  = xs + n;
        int* ssrc   = (int*)(h2s + n);
        int* sdst   = ssrc + e;
        int* counts = sdst + e;
        int* offs   = counts + M;
        int* bstart = offs + M;

        k_hist    <<<NTILES, NTS, 0, stream>>>(dst, e, nbuck, counts);
        k_scan    <<<1,      NTS, 0, stream>>>(counts, offs, bstart, nbuck, e);
        k_sortB   <<<NTILES, NTS, 0, stream>>>(src, dst, e, nbuck, offs, ssrc, sdst);
        k_deg_prep<<<nbuck,  NTE, 0, stream>>>(sdst, bstart, x, dinv, xs, n);
        k_scat_mlp<<<nbuck,  NTE, 0, stream>>>(ssrc, sdst, bstart, dinv, xs,
                                               W1, b1, W2, h2s, n);
        k_scat_out<<<nbuck,  NTE, 0, stream>>>(ssrc, sdst, bstart, dinv, h2s,
                                               b2, out, n);
    } else {
        const int BT = 256;
        const int gn = (n + BT - 1) / BT;
        const int ge = (e + BT - 1) / BT;
        float* dinv = (float*)d_ws;   // holds deg then dinv
        float* xs   = dinv + n;
        float* h2s  = xs + n;
        float* agg  = h2s + n;
        f_init<<<gn, BT, 0, stream>>>(dinv, agg, n);
        f_deg <<<ge, BT, 0, stream>>>(dst, dinv, e);
        f_prep<<<gn, BT, 0, stream>>>(x, dinv, xs, n);
        f_scat<<<ge, BT, 0, stream>>>(src, dst, xs, agg, e);
        f_mlp <<<gn, BT, 0, stream>>>(dinv, xs, agg, W1, b1, W2, h2s, n);
        f_scat<<<ge, BT, 0, stream>>>(src, dst, h2s, agg, e);
        f_out <<<gn, BT, 0, stream>>>(dinv, h2s, agg, b2, out, n);
    }
}

// Round 6
// 56.986 us; speedup vs baseline: 4.0995x; 1.7575x over previous
//
#include <hip/hip_runtime.h>

#define HIDDEN 64
#define BSN 512          // nodes per bucket (power of 2)
#define LOGB 9
#define NTILES 128       // sort tiles (== scanA block size)
#define NTS 1024         // threads for hist/sort kernels
#define NTE 512          // threads for bucket (edge) kernels == BSN
#define MAXB 4096        // max buckets supported by LDS counters (16 KB)
#define SRCBITS 17       // src id fits in 17 bits (n <= 131072)

__device__ __forceinline__ int wave_incl_scan(int v) {
    const int lane = threadIdx.x & 63;
#pragma unroll
    for (int off = 1; off < 64; off <<= 1) {
        int u = __shfl_up(v, off, 64);
        if (lane >= off) v += u;
    }
    return v;
}

// ---------- pass 1: per-tile per-bucket histogram --------------------------
__global__ __launch_bounds__(NTS) void k_hist(const int* __restrict__ dst, int e,
                                              int nbuck, int* __restrict__ counts) {
    __shared__ int lcnt[MAXB];
    const int t = blockIdx.x;
    for (int i = threadIdx.x; i < nbuck; i += NTS) lcnt[i] = 0;
    __syncthreads();
    const int lo = (int)((long long)e * t / NTILES);
    const int hi = (int)((long long)e * (t + 1) / NTILES);
    for (int i = lo + threadIdx.x; i < hi; i += NTS)
        atomicAdd(&lcnt[dst[i] >> LOGB], 1);
    __syncthreads();
    for (int g = threadIdx.x; g < nbuck; g += NTS)
        counts[g * NTILES + t] = lcnt[g];
}

// ---------- pass 2a: within-bucket exclusive scan (wave shfl) --------------
__global__ __launch_bounds__(NTILES) void k_scanA(const int* __restrict__ counts,
                                                  int* __restrict__ locoffs,
                                                  int* __restrict__ totals) {
    __shared__ int wtot[NTILES / 64];
    const int g = blockIdx.x;
    const int t = threadIdx.x;
    int c = counts[g * NTILES + t];
    int inc = wave_incl_scan(c);
    if ((t & 63) == 63) wtot[t >> 6] = inc;
    __syncthreads();
    int add = 0;
    const int w = t >> 6;
    for (int i = 0; i < w; ++i) add += wtot[i];
    locoffs[g * NTILES + t] = inc + add - c;       // exclusive within bucket
    if (t == NTILES - 1) totals[g] = inc + add;    // bucket total
}

// ---------- pass 2b: scan bucket totals -> bstart --------------------------
__global__ __launch_bounds__(256) void k_scanB(const int* __restrict__ totals,
                                               int* __restrict__ bstart,
                                               int nbuck, int e) {
    __shared__ int wtot[4];
    const int t = threadIdx.x;
    const int chunk = (nbuck + 255) / 256;
    const int lo = t * chunk;
    const int hi = (lo + chunk < nbuck) ? lo + chunk : nbuck;
    int s = 0;
    for (int i = lo; i < hi; ++i) s += totals[i];
    int inc = wave_incl_scan(s);
    if ((t & 63) == 63) wtot[t >> 6] = inc;
    __syncthreads();
    int add = 0;
    const int w = t >> 6;
    for (int i = 0; i < w; ++i) add += wtot[i];
    int run = inc + add - s;   // exclusive over chunks
    for (int i = lo; i < hi; ++i) { bstart[i] = run; run += totals[i]; }
    if (t == 0) bstart[nbuck] = e;
}

// ---------- pass 3: scatter edges into bucket-sorted packed words ----------
__global__ __launch_bounds__(NTS) void k_sortB(const int* __restrict__ src,
                                               const int* __restrict__ dst, int e,
                                               int nbuck,
                                               const int* __restrict__ locoffs,
                                               const int* __restrict__ bstart,
                                               unsigned* __restrict__ sw) {
    __shared__ int loffs[MAXB];
    const int t = blockIdx.x;
    for (int g = threadIdx.x; g < nbuck; g += NTS)
        loffs[g] = bstart[g] + locoffs[g * NTILES + t];
    __syncthreads();
    const int lo = (int)((long long)e * t / NTILES);
    const int hi = (int)((long long)e * (t + 1) / NTILES);
    for (int i = lo + threadIdx.x; i < hi; i += NTS) {
        int d = dst[i];
        int g = d >> LOGB;
        int pos = atomicAdd(&loffs[g], 1);
        sw[pos] = ((unsigned)(d - (g << LOGB)) << SRCBITS) | (unsigned)src[i];
    }
}

// ---------- pass 4: degree -> dinv, xs  (one block per bucket) -------------
__global__ __launch_bounds__(NTE) void k_deg_prep(const unsigned* __restrict__ sw,
                                                  const int* __restrict__ bstart,
                                                  const float* __restrict__ x,
                                                  float* __restrict__ dinv,
                                                  float* __restrict__ xs, int n) {
    __shared__ float lacc[BSN];
    const int g = blockIdx.x;
    lacc[threadIdx.x] = 0.0f;
    __syncthreads();
    const int lo = bstart[g], hi = bstart[g + 1];
    for (int i = lo + threadIdx.x; i < hi; i += NTE)
        atomicAdd(&lacc[sw[i] >> SRCBITS], 1.0f);
    __syncthreads();
    const int node = (g << LOGB) + threadIdx.x;
    if (node < n) {
        float d = rsqrtf(1.0f + lacc[threadIdx.x]);   // +1 = self-loop
        dinv[node] = d;
        xs[node] = x[node] * d;
    }
}

// ---------- pass 5: scatter xs -> agg -> MLP -> h2s ------------------------
__global__ __launch_bounds__(NTE) void k_scat_mlp(const unsigned* __restrict__ sw,
    const int* __restrict__ bstart, const float* __restrict__ dinv,
    const float* __restrict__ xs, const float* __restrict__ W1,
    const float* __restrict__ b1, const float* __restrict__ W2,
    float* __restrict__ h2s, int n) {
    __shared__ float lacc[BSN];
    __shared__ float swt[3 * HIDDEN];
    const int g = blockIdx.x;
    lacc[threadIdx.x] = 0.0f;
    if (threadIdx.x < 3 * HIDDEN) {
        int j = threadIdx.x;
        swt[j] = (j < HIDDEN) ? W1[j]
               : (j < 2 * HIDDEN) ? b1[j - HIDDEN] : W2[j - 2 * HIDDEN];
    }
    __syncthreads();
    const int lo = bstart[g], hi = bstart[g + 1];
    for (int i = lo + threadIdx.x; i < hi; i += NTE) {
        unsigned w = sw[i];
        atomicAdd(&lacc[w >> SRCBITS], xs[w & ((1u << SRCBITS) - 1)]);
    }
    __syncthreads();
    const int node = (g << LOGB) + threadIdx.x;
    if (node < n) {
        float di = dinv[node];
        float s1 = di * (lacc[threadIdx.x] + xs[node]);  // xs = self-loop term
        float h = 0.0f;
#pragma unroll
        for (int j = 0; j < HIDDEN; ++j)
            h += fmaxf(fmaf(s1, swt[j], swt[HIDDEN + j]), 0.0f) * swt[2 * HIDDEN + j];
        h2s[node] = h * di;
    }
}

// ---------- pass 6: scatter h2s -> agg -> out ------------------------------
__global__ __launch_bounds__(NTE) void k_scat_out(const unsigned* __restrict__ sw,
    const int* __restrict__ bstart, const float* __restrict__ dinv,
    const float* __restrict__ h2s, const float* __restrict__ b2,
    float* __restrict__ out, int n) {
    __shared__ float lacc[BSN];
    const int g = blockIdx.x;
    lacc[threadIdx.x] = 0.0f;
    __syncthreads();
    const int lo = bstart[g], hi = bstart[g + 1];
    for (int i = lo + threadIdx.x; i < hi; i += NTE) {
        unsigned w = sw[i];
        atomicAdd(&lacc[w >> SRCBITS], h2s[w & ((1u << SRCBITS) - 1)]);
    }
    __syncthreads();
    const int node = (g << LOGB) + threadIdx.x;
    if (node < n)
        out[node] = dinv[node] * (lacc[threadIdx.x] + h2s[node]) + b2[0];
}

// ---------------- fallback: single-copy global-atomic path ----------------
__global__ void f_init(float* deg, float* agg, int n) {
    int i = blockIdx.x * blockDim.x + threadIdx.x;
    if (i < n) { deg[i] = 1.0f; agg[i] = 0.0f; }
}
__global__ void f_deg(const int* __restrict__ dst, float* deg, int e) {
    int i = blockIdx.x * blockDim.x + threadIdx.x;
    if (i < e) atomicAdd(&deg[dst[i]], 1.0f);
}
__global__ void f_prep(const float* __restrict__ x, float* deg,
                       float* __restrict__ xs, int n) {
    int i = blockIdx.x * blockDim.x + threadIdx.x;
    if (i < n) { float d = rsqrtf(deg[i]); deg[i] = d; xs[i] = x[i] * d; }
}
__global__ void f_scat(const int* __restrict__ src, const int* __restrict__ dst,
                       const float* __restrict__ vals, float* agg, int e) {
    int i = blockIdx.x * blockDim.x + threadIdx.x;
    if (i < e) atomicAdd(&agg[dst[i]], vals[src[i]]);
}
__global__ void f_mlp(const float* __restrict__ dinv, const float* __restrict__ xs,
                      float* agg, const float* __restrict__ W1,
                      const float* __restrict__ b1, const float* __restrict__ W2,
                      float* __restrict__ h2s, int n) {
    __shared__ float sW1[HIDDEN], sb1[HIDDEN], sW2[HIDDEN];
    if (threadIdx.x < HIDDEN) {
        sW1[threadIdx.x] = W1[threadIdx.x];
        sb1[threadIdx.x] = b1[threadIdx.x];
        sW2[threadIdx.x] = W2[threadIdx.x];
    }
    __syncthreads();
    int i = blockIdx.x * blockDim.x + threadIdx.x;
    if (i >= n) return;
    float di = dinv[i];
    float s1 = di * (agg[i] + xs[i]);
    agg[i] = 0.0f;
    float h = 0.0f;
#pragma unroll
    for (int j = 0; j < HIDDEN; ++j)
        h += fmaxf(fmaf(s1, sW1[j], sb1[j]), 0.0f) * sW2[j];
    h2s[i] = h * di;
}
__global__ void f_out(const float* __restrict__ dinv, const float* __restrict__ h2s,
                      const float* __restrict__ agg, const float* __restrict__ b2,
                      float* __restrict__ out, int n) {
    int i = blockIdx.x * blockDim.x + threadIdx.x;
    if (i < n) out[i] = dinv[i] * (agg[i] + h2s[i]) + b2[0];
}

// ---------------------------------------------------------------------------
extern "C" void kernel_launch(void* const* d_in, const int* in_sizes, int n_in,
                              void* d_out, int out_size, void* d_ws, size_t ws_size,
                              hipStream_t stream) {
    const float* x  = (const float*)d_in[0];
    const int*   ei = (const int*)d_in[1];   // [2, E] int32
    const float* W1 = (const float*)d_in[2];
    const float* b1 = (const float*)d_in[3];
    const float* W2 = (const float*)d_in[4];
    const float* b2 = (const float*)d_in[5];
    float* out = (float*)d_out;

    const int n = in_sizes[0];
    const int e = in_sizes[1] / 2;
    const int* src = ei;
    const int* dst = ei + e;

    const int nbuck = (n + BSN - 1) >> LOGB;
    const int M = nbuck * NTILES;
    // ws: dinv[n], xs[n], h2s[n] | sw[e] | counts[M], locoffs[M], totals[nbuck],
    //     bstart[nbuck+1]
    const size_t need = ((size_t)3 * n + (size_t)e + 2 * (size_t)M + 2 * nbuck + 1)
                        * sizeof(int);

    if (nbuck >= 1 && nbuck <= MAXB && n <= (1 << SRCBITS) && ws_size >= need) {
        float* dinv    = (float*)d_ws;
        float* xs      = dinv + n;
        float* h2s     = xs + n;
        unsigned* sw   = (unsigned*)(h2s + n);
        int* counts    = (int*)(sw + e);
        int* locoffs   = counts + M;
        int* totals    = locoffs + M;
        int* bstart    = totals + nbuck;

        k_hist    <<<NTILES, NTS,    0, stream>>>(dst, e, nbuck, counts);
        k_scanA   <<<nbuck,  NTILES, 0, stream>>>(counts, locoffs, totals);
        k_scanB   <<<1,      256,    0, stream>>>(totals, bstart, nbuck, e);
        k_sortB   <<<NTILES, NTS,    0, stream>>>(src, dst, e, nbuck, locoffs,
                                                  bstart, sw);
        k_deg_prep<<<nbuck,  NTE,    0, stream>>>(sw, bstart, x, dinv, xs, n);
        k_scat_mlp<<<nbuck,  NTE,    0, stream>>>(sw, bstart, dinv, xs,
                                                  W1, b1, W2, h2s, n);
        k_scat_out<<<nbuck,  NTE,    0, stream>>>(sw, bstart, dinv, h2s,
                                                  b2, out, n);
    } else {
        const int BT = 256;
        const int gn = (n + BT - 1) / BT;
        const int ge = (e + BT - 1) / BT;
        float* dinv = (float*)d_ws;   // holds deg then dinv
        float* xs   = dinv + n;
        float* h2s  = xs + n;
        float* agg  = h2s + n;
        f_init<<<gn, BT, 0, stream>>>(dinv, agg, n);
        f_deg <<<ge, BT, 0, stream>>>(dst, dinv, e);
        f_prep<<<gn, BT, 0, stream>>>(x, dinv, xs, n);
        f_scat<<<ge, BT, 0, stream>>>(src, dst, xs, agg, e);
        f_mlp <<<gn, BT, 0, stream>>>(dinv, xs, agg, W1, b1, W2, h2s, n);
        f_scat<<<ge, BT, 0, stream>>>(src, dst, h2s, agg, e);
        f_out <<<gn, BT, 0, stream>>>(dinv, h2s, agg, b2, out, n);
    }
}